// Round 5
// baseline (771.120 us; speedup 1.0000x reference)
//
#include <hip/hip_runtime.h>
#include <math.h>

typedef unsigned short u16;
typedef unsigned int u32;
typedef __attribute__((ext_vector_type(8))) short short8;
typedef __attribute__((ext_vector_type(2))) unsigned int u32x2;
typedef __attribute__((ext_vector_type(4))) float f32x4;

#define C_ 128
#define NTOK 200704   // B*H*W = 64*56*56
#define NMT  12544    // NTOK/16 M-tiles
#define NWIN 4096     // B * 64
#define SCALE_ 0.17677669529663687f

static __device__ __forceinline__ float bf2f(u16 u) {
    return __uint_as_float(((u32)u) << 16);
}
static __device__ __forceinline__ u16 f2bf(float f) {
    u32 u = __float_as_uint(f);
    u32 r = u + 0x7FFFu + ((u >> 16) & 1u);
    return (u16)(r >> 16);
}
static __device__ __forceinline__ u32 cvtpk(float a, float b) {
    u32 r;
    asm("v_cvt_pk_bf16_f32 %0, %1, %2" : "=v"(r) : "v"(a), "v"(b));
    return r;
}
// Pin a value into VGPRs: opaque asm "may modify" it, so the compiler cannot
// rematerialize the original load inside the consuming loop.
static __device__ __forceinline__ void pin(short8& v) { asm volatile("" : "+v"(v)); }
static __device__ __forceinline__ void pin(float& v)  { asm volatile("" : "+v"(v)); }

// ---------------- plain weight transpose to bf16 [N][K] ----------------
__global__ void k_transpose(const float* __restrict__ W, u16* __restrict__ Wt, int K, int N) {
    int i = blockIdx.x * 256 + threadIdx.x;
    if (i >= K * N) return;
    int k = i / N, n = i % N;
    Wt[(size_t)n * K + k] = f2bf(W[i]);
}

// ---------------- LN-folding prep: Wt[n][k]=bf16(W[k][n]*g[k]); bout[n]=b[n]+sum_k be[k]*W[k][n]
__global__ __launch_bounds__(128) void k_prep(const float* __restrict__ W,
                                              const float* __restrict__ g,
                                              const float* __restrict__ be,
                                              const float* __restrict__ b,
                                              u16* __restrict__ Wt,
                                              float* __restrict__ bout, int N) {
    int n = blockIdx.x, k = threadIdx.x;  // K = 128 fixed
    float w = W[(size_t)k * N + n];
    Wt[(size_t)n * 128 + k] = f2bf(w * g[k]);
    __shared__ float red[128];
    red[k] = be[k] * w;
    __syncthreads();
    for (int s = 64; s > 0; s >>= 1) {
        if (k < s) red[k] += red[k + s];
        __syncthreads();
    }
    if (k == 0) bout[n] = b[n] + red[0];
}

// ---------------- B-fragment loader ----------------
template <int KD, int NN>
static __device__ __forceinline__ void load_bfrag(const u16* __restrict__ Wt, int col0, int lane,
                                                  short8 (&bf)[NN][KD / 32]) {
    constexpr int NK = KD / 32;
    const int colb = lane & 15, kb = (lane >> 4) * 8;
#pragma unroll
    for (int n = 0; n < NN; ++n)
#pragma unroll
        for (int ks = 0; ks < NK; ++ks) {
            bf[n][ks] = *(const short8*)(Wt + (size_t)(col0 + n * 16 + colb) * KD + ks * 32 + kb);
            pin(bf[n][ks]);
        }
}

// ---------------- QKV GEMM, fused LN1 + shift + window partition ----------------
__global__ __launch_bounds__(512) void k_qkv(const float* __restrict__ x,
                                             const u16* __restrict__ qkvT,
                                             const float* __restrict__ bq,
                                             u16* __restrict__ qkvO) {
    int lane = threadIdx.x & 63, wv = threadIdx.x >> 6;
    int colb = lane & 15, q4 = lane >> 4;
    int col0 = wv * 48;
    short8 bfr[3][4];
    load_bfrag<128, 3>(qkvT, col0, lane, bfr);
    float bias[3];
#pragma unroll
    for (int n = 0; n < 3; ++n) { bias[n] = bq[col0 + n * 16 + colb]; pin(bias[n]); }
#pragma unroll 1
    for (int mt = blockIdx.x; mt < NMT; mt += gridDim.x) {
        int m = mt * 16 + colb;
        int wn = m / 49, nn = m - wn * 49;
        int b = wn >> 6, wl = wn & 63;
        int ys = (wl >> 3) * 7 + nn / 7, xs = (wl & 7) * 7 + nn % 7;
        int y = ys + 3; if (y >= 56) y -= 56;
        int xx = xs + 3; if (xx >= 56) xx -= 56;
        const float* px = x + ((size_t)b * 3136 + y * 56 + xx) * 128 + q4 * 8;
        float cur[32];
#pragma unroll
        for (int ks = 0; ks < 4; ++ks) {
            *(float4*)(cur + ks * 8)     = *(const float4*)(px + ks * 32);
            *(float4*)(cur + ks * 8 + 4) = *(const float4*)(px + ks * 32 + 4);
        }
        float s = 0.f, s2 = 0.f;
#pragma unroll
        for (int i = 0; i < 32; ++i) { s += cur[i]; s2 += cur[i] * cur[i]; }
        s  += __shfl_xor(s, 16, 64);  s  += __shfl_xor(s, 32, 64);
        s2 += __shfl_xor(s2, 16, 64); s2 += __shfl_xor(s2, 32, 64);
        float mu = s * (1.f / 128.f);
        float rs = rsqrtf(s2 * (1.f / 128.f) - mu * mu + 1e-3f);
        short8 af[4];
#pragma unroll
        for (int ks = 0; ks < 4; ++ks)
#pragma unroll
            for (int e = 0; e < 8; ++e)
                af[ks][e] = (short)f2bf((cur[ks * 8 + e] - mu) * rs);
        f32x4 acc[3];
#pragma unroll
        for (int n = 0; n < 3; ++n) acc[n] = (f32x4){0.f, 0.f, 0.f, 0.f};
#pragma unroll
        for (int ks = 0; ks < 4; ++ks)
#pragma unroll
            for (int n = 0; n < 3; ++n)
                acc[n] = __builtin_amdgcn_mfma_f32_16x16x32_bf16(af[ks], bfr[n][ks], acc[n], 0, 0, 0);
#pragma unroll
        for (int n = 0; n < 3; ++n) {
            int col = col0 + n * 16 + colb;
#pragma unroll
            for (int r = 0; r < 4; ++r)
                qkvO[(size_t)(mt * 16 + q4 * 4 + r) * 384 + col] = f2bf(acc[n][r] + bias[n]);
        }
    }
}

// ---------------- MFMA window attention: 1 block/window, 1 wave/head ----------------
__global__ __launch_bounds__(256) void k_attn(const u16* __restrict__ qkv,
                                              const float* __restrict__ relTab,
                                              u16* __restrict__ outA) {
    __shared__ u16 Pl[4 * 64 * 64];      // per-head P [64 r][64 j], XOR-swizzled, 32KB
    __shared__ u16 Vt[4 * 32 * 72];      // V transposed [h][d][j], stride 72, 18KB
    __shared__ float biasl[676];
    __shared__ int regl[64];
    int tid = threadIdx.x;
    int w = blockIdx.x;
    int wi = w & 63, wr = wi >> 3, wc = wi & 7;
    const u16* base = qkv + (size_t)w * 49 * 384;

    for (int task = tid; task < 1024; task += 256) {
        int row = task >> 3, jo = (task & 7) * 8;
        int h = row >> 5, d = row & 31;
        short8 v;
#pragma unroll
        for (int e = 0; e < 8; ++e) {
            int j = jo + e;
            v[e] = (j < 49) ? (short)base[j * 384 + 256 + h * 32 + d] : (short)0;
        }
        *(short8*)(Vt + row * 72 + jo) = v;
    }
    for (int idx = tid; idx < 676; idx += 256) biasl[idx] = relTab[idx];
    if (tid < 64) {
        int t = tid;
        int ty = t / 7, tx = t - ty * 7;
        int gy = wr * 7 + ty, gx = wc * 7 + tx;
        int rg = (gy < 49 ? 0 : (gy < 53 ? 1 : 2)) * 3 + (gx < 49 ? 0 : (gx < 53 ? 1 : 2));
        regl[t] = (t < 49) ? rg : 99;
    }
    __syncthreads();

    int lane = tid & 63, h = tid >> 6;
    int colb = lane & 15, q4 = lane >> 4;

    // ---- QK^T (swapped): acc[mt][nt] = S^T[j = mt*16+q4*4+reg][r = nt*16+colb]
    short8 ka[4], qb[4];
#pragma unroll
    for (int t = 0; t < 4; ++t) {
        int row = w * 49 + t * 16 + colb;
        if (row > NTOK - 1) row = NTOK - 1;
        ka[t] = *(const short8*)(qkv + (size_t)row * 384 + 128 + h * 32 + q4 * 8);
        qb[t] = *(const short8*)(qkv + (size_t)row * 384 + h * 32 + q4 * 8);
    }
    float s[4][4][4];  // [mt][nt][reg]
    {
        f32x4 acc[4][4];
#pragma unroll
        for (int mt = 0; mt < 4; ++mt)
#pragma unroll
            for (int nt = 0; nt < 4; ++nt)
                acc[mt][nt] = __builtin_amdgcn_mfma_f32_16x16x32_bf16(
                    ka[mt], qb[nt], (f32x4){0.f, 0.f, 0.f, 0.f}, 0, 0, 0);
        int bc[4], rc[4];
#pragma unroll
        for (int nt = 0; nt < 4; ++nt) {
            int c = nt * 16 + colb;
            int cc = c < 49 ? c : 48;
            int yc = cc / 7, xc = cc - yc * 7;
            bc[nt] = ((yc + 6) * 13 + (xc + 6)) * 4 + h;
            rc[nt] = regl[cc];
        }
#pragma unroll
        for (int mt = 0; mt < 4; ++mt)
#pragma unroll
            for (int reg = 0; reg < 4; ++reg) {
                int j = mt * 16 + q4 * 4 + reg;
                int jj = j < 49 ? j : 48;
                int yj = jj / 7, xj = jj - yj * 7;
                int oj = (yj * 13 + xj) * 4;
                int rj = regl[jj];
#pragma unroll
                for (int nt = 0; nt < 4; ++nt) {
                    float v = acc[mt][nt][reg] * SCALE_ + biasl[bc[nt] - oj];
                    if (rj != rc[nt]) v -= 100.f;
                    s[mt][nt][reg] = (j < 49) ? v : -1e30f;
                }
            }
    }
    float sm[4];
#pragma unroll
    for (int nt = 0; nt < 4; ++nt) {
        float m = s[0][nt][0];
#pragma unroll
        for (int mt = 0; mt < 4; ++mt)
#pragma unroll
            for (int reg = 0; reg < 4; ++reg) m = fmaxf(m, s[mt][nt][reg]);
        m = fmaxf(m, __shfl_xor(m, 16, 64));
        m = fmaxf(m, __shfl_xor(m, 32, 64));
        float t = 0.f;
#pragma unroll
        for (int mt = 0; mt < 4; ++mt)
#pragma unroll
            for (int reg = 0; reg < 4; ++reg) {
                float e = __expf(s[mt][nt][reg] - m);
                s[mt][nt][reg] = e;
                t += e;
            }
        t += __shfl_xor(t, 16, 64);
        t += __shfl_xor(t, 32, 64);
        sm[nt] = 1.f / t;
    }
    u16* Ph = Pl + h * 4096;
#pragma unroll
    for (int nt = 0; nt < 4; ++nt) {
        int r = nt * 16 + colb;
        u32 sw = (u32)(r & 7) << 4;
#pragma unroll
        for (int mt = 0; mt < 4; ++mt) {
            u32x2 pk;
            pk[0] = cvtpk(s[mt][nt][0] * sm[nt], s[mt][nt][1] * sm[nt]);
            pk[1] = cvtpk(s[mt][nt][2] * sm[nt], s[mt][nt][3] * sm[nt]);
            u32 off = ((u32)((r * 64 + mt * 16 + q4 * 4) * 2)) ^ sw;
            *(u32x2*)((char*)Ph + off) = pk;
        }
    }
    short8 vb[2][2];
#pragma unroll
    for (int no = 0; no < 2; ++no)
#pragma unroll
        for (int ks = 0; ks < 2; ++ks)
            vb[no][ks] = *(const short8*)(Vt + (h * 32 + no * 16 + colb) * 72 + ks * 32 + q4 * 8);
#pragma unroll
    for (int mo = 0; mo < 4; ++mo) {
        int r = mo * 16 + colb;
        u32 sw = (u32)(r & 7) << 4;
        short8 pa[2];
#pragma unroll
        for (int ks = 0; ks < 2; ++ks) {
            u32 off = ((u32)((r * 64 + ks * 32 + q4 * 8) * 2)) ^ sw;
            pa[ks] = *(const short8*)((const char*)Ph + off);
        }
        f32x4 o0 = {0.f, 0.f, 0.f, 0.f}, o1 = {0.f, 0.f, 0.f, 0.f};
#pragma unroll
        for (int ks = 0; ks < 2; ++ks) {
            o0 = __builtin_amdgcn_mfma_f32_16x16x32_bf16(pa[ks], vb[0][ks], o0, 0, 0, 0);
            o1 = __builtin_amdgcn_mfma_f32_16x16x32_bf16(pa[ks], vb[1][ks], o1, 0, 0, 0);
        }
#pragma unroll
        for (int reg = 0; reg < 4; ++reg) {
            int orow = mo * 16 + q4 * 4 + reg;
            if (orow < 49) {
                size_t o = ((size_t)w * 49 + orow) * 128 + h * 32;
                outA[o + colb]      = f2bf(o0[reg]);
                outA[o + 16 + colb] = f2bf(o1[reg]);
            }
        }
    }
}

// ---------------- proj GEMM + reverse/roll + residual -> x1 (bf16) ----------------
__global__ __launch_bounds__(512) void k_proj(const u16* __restrict__ attnO,
                                              const u16* __restrict__ projT,
                                              const float* __restrict__ bproj,
                                              const float* __restrict__ x,
                                              u16* __restrict__ x1) {
    int lane = threadIdx.x & 63, wv = threadIdx.x >> 6;
    int colb = lane & 15, q4 = lane >> 4;
    int col0 = wv * 16;
    short8 bfr[1][4];
    load_bfrag<128, 1>(projT, col0, lane, bfr);
    float bias = bproj[col0 + colb];
    pin(bias);
#pragma unroll 1
    for (int mt = blockIdx.x; mt < NMT; mt += gridDim.x) {
        const u16* pa = attnO + (size_t)(mt * 16 + colb) * 128 + q4 * 8;
        short8 af[4];
#pragma unroll
        for (int ks = 0; ks < 4; ++ks) af[ks] = *(const short8*)(pa + ks * 32);
        f32x4 acc = {0.f, 0.f, 0.f, 0.f};
#pragma unroll
        for (int ks = 0; ks < 4; ++ks)
            acc = __builtin_amdgcn_mfma_f32_16x16x32_bf16(af[ks], bfr[0][ks], acc, 0, 0, 0);
        int col = col0 + colb;
#pragma unroll
        for (int r = 0; r < 4; ++r) {
            int m = mt * 16 + q4 * 4 + r;
            int wn = m / 49, nn = m - wn * 49;
            int b = wn >> 6, wl = wn & 63;
            int ys = (wl >> 3) * 7 + nn / 7, xs = (wl & 7) * 7 + nn % 7;
            int y = ys + 3; if (y >= 56) y -= 56;
            int xx = xs + 3; if (xx >= 56) xx -= 56;
            size_t tok = (size_t)b * 3136 + y * 56 + xx;
            x1[tok * 128 + col] = f2bf(acc[r] + bias + x[tok * 128 + col]);
        }
    }
}

// ---------------- FC1, fused LN2 + exact GELU: wave owns 64 cols ----------------
__global__ __launch_bounds__(512) void k_fc1(const u16* __restrict__ x1,
                                             const u16* __restrict__ fc1T,
                                             const float* __restrict__ b1,
                                             u16* __restrict__ h1) {
    int lane = threadIdx.x & 63, wv = threadIdx.x >> 6;
    int colb = lane & 15, q4 = lane >> 4;
    int col0 = wv * 64;
    short8 bfr[4][4];
    load_bfrag<128, 4>(fc1T, col0, lane, bfr);
    float bias[4];
#pragma unroll
    for (int n = 0; n < 4; ++n) { bias[n] = b1[col0 + n * 16 + colb]; pin(bias[n]); }
#pragma unroll 1
    for (int mt = blockIdx.x; mt < NMT; mt += gridDim.x) {
        const u16* px = x1 + (size_t)(mt * 16 + colb) * 128 + q4 * 8;
        short8 raw[4];
#pragma unroll
        for (int ks = 0; ks < 4; ++ks) raw[ks] = *(const short8*)(px + ks * 32);
        float cur[32];
#pragma unroll
        for (int ks = 0; ks < 4; ++ks)
#pragma unroll
            for (int e = 0; e < 8; ++e) cur[ks * 8 + e] = bf2f((u16)raw[ks][e]);
        float s = 0.f, s2 = 0.f;
#pragma unroll
        for (int i = 0; i < 32; ++i) { s += cur[i]; s2 += cur[i] * cur[i]; }
        s  += __shfl_xor(s, 16, 64);  s  += __shfl_xor(s, 32, 64);
        s2 += __shfl_xor(s2, 16, 64); s2 += __shfl_xor(s2, 32, 64);
        float mu = s * (1.f / 128.f);
        float rs = rsqrtf(s2 * (1.f / 128.f) - mu * mu + 1e-3f);
        short8 af[4];
#pragma unroll
        for (int ks = 0; ks < 4; ++ks)
#pragma unroll
            for (int e = 0; e < 8; ++e)
                af[ks][e] = (short)f2bf((cur[ks * 8 + e] - mu) * rs);
        f32x4 acc[4];
#pragma unroll
        for (int n = 0; n < 4; ++n) acc[n] = (f32x4){0.f, 0.f, 0.f, 0.f};
#pragma unroll
        for (int ks = 0; ks < 4; ++ks)
#pragma unroll
            for (int n = 0; n < 4; ++n)
                acc[n] = __builtin_amdgcn_mfma_f32_16x16x32_bf16(af[ks], bfr[n][ks], acc[n], 0, 0, 0);
#pragma unroll
        for (int n = 0; n < 4; ++n) {
            int col = col0 + n * 16 + colb;
#pragma unroll
            for (int r = 0; r < 4; ++r) {
                float t = acc[n][r] + bias[n];
                float g = 0.5f * t * (1.f + erff(t * 0.70710678118654752f));
                h1[(size_t)(mt * 16 + q4 * 4 + r) * 512 + col] = f2bf(g);
            }
        }
    }
}

// ---------------- FC2 + final residual ----------------
__global__ __launch_bounds__(512) void k_fc2(const u16* __restrict__ h1,
                                             const u16* __restrict__ fc2T,
                                             const float* __restrict__ b2,
                                             const u16* __restrict__ x1,
                                             float* __restrict__ out) {
    int lane = threadIdx.x & 63, wv = threadIdx.x >> 6;
    int colb = lane & 15, q4 = lane >> 4;
    int col0 = wv * 16;
    short8 bfr[1][16];
    load_bfrag<512, 1>(fc2T, col0, lane, bfr);
    float bias = b2[col0 + colb];
    pin(bias);
#pragma unroll 1
    for (int mt = blockIdx.x; mt < NMT; mt += gridDim.x) {
        const u16* pa = h1 + (size_t)(mt * 16 + colb) * 512 + q4 * 8;
        short8 af[16];
#pragma unroll
        for (int ks = 0; ks < 16; ++ks) af[ks] = *(const short8*)(pa + ks * 32);
        // two accumulator chains to break serial MFMA dependency
        f32x4 acc0 = {0.f, 0.f, 0.f, 0.f}, acc1 = {0.f, 0.f, 0.f, 0.f};
#pragma unroll
        for (int ks = 0; ks < 16; ks += 2) {
            acc0 = __builtin_amdgcn_mfma_f32_16x16x32_bf16(af[ks],     bfr[0][ks],     acc0, 0, 0, 0);
            acc1 = __builtin_amdgcn_mfma_f32_16x16x32_bf16(af[ks + 1], bfr[0][ks + 1], acc1, 0, 0, 0);
        }
        int col = col0 + colb;
#pragma unroll
        for (int r = 0; r < 4; ++r) {
            size_t m = (size_t)mt * 16 + q4 * 4 + r;
            out[m * 128 + col] = bf2f(x1[m * 128 + col]) + acc0[r] + acc1[r] + bias;
        }
    }
}

extern "C" void kernel_launch(void* const* d_in, const int* in_sizes, int n_in,
                              void* d_out, int out_size, void* d_ws, size_t ws_size,
                              hipStream_t stream) {
    const float* x    = (const float*)d_in[0];
    const float* g1   = (const float*)d_in[1];
    const float* be1  = (const float*)d_in[2];
    const float* Wqkv = (const float*)d_in[3];
    const float* bqkv = (const float*)d_in[4];
    const float* relT = (const float*)d_in[5];
    const float* Wproj= (const float*)d_in[6];
    const float* bproj= (const float*)d_in[7];
    const float* g2   = (const float*)d_in[8];
    const float* be2  = (const float*)d_in[9];
    const float* Wfc1 = (const float*)d_in[10];
    const float* bfc1 = (const float*)d_in[11];
    const float* Wfc2 = (const float*)d_in[12];
    const float* bfc2 = (const float*)d_in[13];
    float* out = (float*)d_out;
    char* ws = (char*)d_ws;

    u16* qkvb  = (u16*)(ws + 0);              // 154,140,672  dead after k_attn
    u16* attnO = (u16*)(ws + 154140672ULL);   //  51,380,224  dead after k_proj
    u16* x1    = (u16*)(ws + 205520896ULL);   //  51,380,224  lives to k_fc2
    u16* h1    = (u16*)(ws + 0);              // 205,520,896  overwrites qkvb/attnO
    char* wb   = ws + 256901120ULL;
    u16* qkvT  = (u16*)(wb);                  // 98,304
    float* bq  = (float*)(wb + 98304);        // 1,536
    u16* fc1T  = (u16*)(wb + 99840);          // 131,072
    float* bf1 = (float*)(wb + 230912);       // 2,048
    u16* projT = (u16*)(wb + 232960);         // 32,768
    u16* fc2T  = (u16*)(wb + 265728);         // 131,072

    k_prep<<<dim3(384), dim3(128), 0, stream>>>(Wqkv, g1, be1, bqkv, qkvT, bq, 384);
    k_prep<<<dim3(512), dim3(128), 0, stream>>>(Wfc1, g2, be2, bfc1, fc1T, bf1, 512);
    k_transpose<<<dim3((128 * 128 + 255) / 256), dim3(256), 0, stream>>>(Wproj, projT, 128, 128);
    k_transpose<<<dim3((512 * 128 + 255) / 256), dim3(256), 0, stream>>>(Wfc2, fc2T, 512, 128);

    k_qkv <<<dim3(784), dim3(512), 0, stream>>>(x, qkvT, bq, qkvb);
    k_attn<<<dim3(NWIN), dim3(256), 0, stream>>>(qkvb, relT, attnO);
    k_proj<<<dim3(784), dim3(512), 0, stream>>>(attnO, projT, bproj, x, x1);
    k_fc1 <<<dim3(784), dim3(512), 0, stream>>>(x1, fc1T, bf1, h1);
    k_fc2 <<<dim3(784), dim3(512), 0, stream>>>(h1, fc2T, bfc2, x1, out);
}

// Round 6
// 418.001 us; speedup vs baseline: 1.8448x; 1.8448x over previous
//
#include <hip/hip_runtime.h>
#include <math.h>

typedef unsigned short u16;
typedef unsigned int u32;
typedef __attribute__((ext_vector_type(8))) short short8;
typedef __attribute__((ext_vector_type(2))) unsigned int u32x2;
typedef __attribute__((ext_vector_type(4))) float f32x4;

#define C_ 128
#define NTOK 200704   // B*H*W = 64*56*56
#define MBLK 1568     // NTOK / 128
#define NWIN 4096     // B * 64
#define SCALE_ 0.17677669529663687f

static __device__ __forceinline__ float bf2f(u16 u) {
    return __uint_as_float(((u32)u) << 16);
}
static __device__ __forceinline__ u16 f2bf(float f) {
    u32 u = __float_as_uint(f);
    u32 r = u + 0x7FFFu + ((u >> 16) & 1u);
    return (u16)(r >> 16);
}
static __device__ __forceinline__ u32 cvtpk(float a, float b) {
    u32 r;
    asm("v_cvt_pk_bf16_f32 %0, %1, %2" : "=v"(r) : "v"(a), "v"(b));
    return r;
}

// ================= weight prep =================
__global__ void k_transpose(const float* __restrict__ W, u16* __restrict__ Wt, int K, int N) {
    int i = blockIdx.x * 256 + threadIdx.x;
    if (i >= K * N) return;
    int k = i / N, n = i % N;
    Wt[(size_t)n * K + k] = f2bf(W[i]);
}

// fc1 prep: Wt[n][k]=bf16(W[k][n]*g2[k]); beff[n]=b[n]+sum be2[k]W[k][n]; csum[n]=sum Wt
__global__ __launch_bounds__(128) void k_prep2(const float* __restrict__ W,
                                               const float* __restrict__ g,
                                               const float* __restrict__ be,
                                               const float* __restrict__ b,
                                               u16* __restrict__ Wt,
                                               float* __restrict__ beff,
                                               float* __restrict__ csum) {
    const int N = 512;
    int n = blockIdx.x, k = threadIdx.x;
    float w = W[(size_t)k * N + n];
    u16 wp = f2bf(w * g[k]);
    Wt[(size_t)n * 128 + k] = wp;
    __shared__ float r1[128], r2[128];
    r1[k] = be[k] * w;
    r2[k] = bf2f(wp);
    __syncthreads();
    for (int s = 64; s > 0; s >>= 1) {
        if (k < s) { r1[k] += r1[k + s]; r2[k] += r2[k + s]; }
        __syncthreads();
    }
    if (k == 0) { beff[n] = b[n] + r1[0]; csum[n] = r2[0]; }
}

// ================= LN1 + roll(-3,-3) + window partition -> xw bf16 =================
__global__ __launch_bounds__(256) void k_ln1(const float* __restrict__ x,
                                             const float* __restrict__ g,
                                             const float* __restrict__ be,
                                             u16* __restrict__ xw) {
    int lane = threadIdx.x & 63, wv = threadIdx.x >> 6;
    int t = blockIdx.x * 4 + wv;
    const float* px = x + (size_t)t * C_;
    float2 v = *(const float2*)(px + lane * 2);
    float s = v.x + v.y;
#pragma unroll
    for (int off = 1; off < 64; off <<= 1) s += __shfl_xor(s, off, 64);
    float mu = s * (1.f / 128.f);
    float dx = v.x - mu, dy = v.y - mu;
    float s2 = dx * dx + dy * dy;
#pragma unroll
    for (int off = 1; off < 64; off <<= 1) s2 += __shfl_xor(s2, off, 64);
    float rs = rsqrtf(s2 * (1.f / 128.f) + 1e-3f);
    float2 gg = *(const float2*)(g + lane * 2);
    float2 bb = *(const float2*)(be + lane * 2);
    float o0 = dx * rs * gg.x + bb.x;
    float o1 = dy * rs * gg.y + bb.y;
    int b = t / 3136, p = t % 3136;
    int y = p / 56, xx = p % 56;
    int ys = y + 53; if (ys >= 56) ys -= 56;
    int xs = xx + 53; if (xs >= 56) xs -= 56;
    int w = (b << 6) | ((ys / 7) << 3) | (xs / 7);
    int n = (ys % 7) * 7 + (xs % 7);
    u16 o[2] = {f2bf(o0), f2bf(o1)};
    *(u32*)(xw + ((size_t)w * 49 + n) * C_ + lane * 2) = *(u32*)o;
}

// ================= LDS-staged block GEMM core =================
// Tile: 128 rows x 128 k, bf16, XOR swizzle: byte ^= (row&7)<<4.
static __device__ __forceinline__ void stage_tile(char* lds, const char* src, int row_stride, int tid) {
#pragma unroll
    for (int i = 0; i < 4; ++i) {
        int chunk = tid + i * 512;
        int row = chunk >> 4, k16 = (chunk & 15) << 4;
        short8 v = *(const short8*)(src + (size_t)row * row_stride + k16);
        *(short8*)(lds + (((row << 8) + k16) ^ ((row & 7) << 4))) = v;
    }
}
static __device__ __forceinline__ short8 ldsfrag(const char* lds, int row, int kb) {
    return *(const short8*)(lds + (((row << 8) + kb) ^ ((row & 7) << 4)));
}
template <int MR, int NR>
static __device__ __forceinline__ void mfma_core(const char* As, const char* Bs,
                                                 int m0, int n0, int colb, int q4,
                                                 f32x4 (&acc)[MR][NR]) {
#pragma unroll
    for (int ks = 0; ks < 4; ++ks) {
        int kb = ks * 64 + q4 * 16;
        short8 a[MR], b[NR];
#pragma unroll
        for (int m = 0; m < MR; ++m) a[m] = ldsfrag(As, m0 + m * 16 + colb, kb);
#pragma unroll
        for (int n = 0; n < NR; ++n) b[n] = ldsfrag(Bs, n0 + n * 16 + colb, kb);
#pragma unroll
        for (int m = 0; m < MR; ++m)
#pragma unroll
            for (int n = 0; n < NR; ++n)
                acc[m][n] = __builtin_amdgcn_mfma_f32_16x16x32_bf16(a[m], b[n], acc[m][n], 0, 0, 0);
    }
}

// ================= QKV GEMM: xw[M,128] x qkvT[384,128]^T, grid (1568, 3) =================
__global__ __launch_bounds__(512) void g_qkv(const u16* __restrict__ xw,
                                             const u16* __restrict__ qkvT,
                                             const float* __restrict__ bq,
                                             u16* __restrict__ out) {
    __shared__ __align__(16) char As[32768], Bs[32768];
    int tid = threadIdx.x;
    int mb = blockIdx.x, nb = blockIdx.y;
    stage_tile(As, (const char*)(xw + (size_t)mb * 128 * 128), 256, tid);
    stage_tile(Bs, (const char*)(qkvT + (size_t)nb * 128 * 128), 256, tid);
    __syncthreads();
    int lane = tid & 63, wv = tid >> 6, colb = lane & 15, q4 = lane >> 4;
    int m0 = (wv >> 1) * 32, n0 = (wv & 1) * 64;
    f32x4 acc[2][4] = {};
    mfma_core<2, 4>(As, Bs, m0, n0, colb, q4, acc);
#pragma unroll
    for (int nf = 0; nf < 4; ++nf) {
        int col = nb * 128 + n0 + nf * 16 + colb;
        float bb = bq[col];
#pragma unroll
        for (int mf = 0; mf < 2; ++mf)
#pragma unroll
            for (int r = 0; r < 4; ++r) {
                int row = mb * 128 + m0 + mf * 16 + q4 * 4 + r;
                out[(size_t)row * 384 + col] = f2bf(acc[mf][nf][r] + bb);
            }
    }
}

// ================= MFMA window attention (unchanged) =================
__global__ __launch_bounds__(256) void k_attn(const u16* __restrict__ qkv,
                                              const float* __restrict__ relTab,
                                              u16* __restrict__ outA) {
    __shared__ u16 Pl[4 * 64 * 64];
    __shared__ u16 Vt[4 * 32 * 72];
    __shared__ float biasl[676];
    __shared__ int regl[64];
    int tid = threadIdx.x;
    int w = blockIdx.x;
    int wi = w & 63, wr = wi >> 3, wc = wi & 7;
    const u16* base = qkv + (size_t)w * 49 * 384;

    for (int task = tid; task < 1024; task += 256) {
        int row = task >> 3, jo = (task & 7) * 8;
        int h = row >> 5, d = row & 31;
        short8 v;
#pragma unroll
        for (int e = 0; e < 8; ++e) {
            int j = jo + e;
            v[e] = (j < 49) ? (short)base[j * 384 + 256 + h * 32 + d] : (short)0;
        }
        *(short8*)(Vt + row * 72 + jo) = v;
    }
    for (int idx = tid; idx < 676; idx += 256) biasl[idx] = relTab[idx];
    if (tid < 64) {
        int t = tid;
        int ty = t / 7, tx = t - ty * 7;
        int gy = wr * 7 + ty, gx = wc * 7 + tx;
        int rg = (gy < 49 ? 0 : (gy < 53 ? 1 : 2)) * 3 + (gx < 49 ? 0 : (gx < 53 ? 1 : 2));
        regl[t] = (t < 49) ? rg : 99;
    }
    __syncthreads();

    int lane = tid & 63, h = tid >> 6;
    int colb = lane & 15, q4 = lane >> 4;

    short8 ka[4], qb[4];
#pragma unroll
    for (int t = 0; t < 4; ++t) {
        int row = w * 49 + t * 16 + colb;
        if (row > NTOK - 1) row = NTOK - 1;
        ka[t] = *(const short8*)(qkv + (size_t)row * 384 + 128 + h * 32 + q4 * 8);
        qb[t] = *(const short8*)(qkv + (size_t)row * 384 + h * 32 + q4 * 8);
    }
    float s[4][4][4];
    {
        f32x4 acc[4][4];
#pragma unroll
        for (int mt = 0; mt < 4; ++mt)
#pragma unroll
            for (int nt = 0; nt < 4; ++nt)
                acc[mt][nt] = __builtin_amdgcn_mfma_f32_16x16x32_bf16(
                    ka[mt], qb[nt], (f32x4){0.f, 0.f, 0.f, 0.f}, 0, 0, 0);
        int bc[4], rc[4];
#pragma unroll
        for (int nt = 0; nt < 4; ++nt) {
            int c = nt * 16 + colb;
            int cc = c < 49 ? c : 48;
            int yc = cc / 7, xc = cc - yc * 7;
            bc[nt] = ((yc + 6) * 13 + (xc + 6)) * 4 + h;
            rc[nt] = regl[cc];
        }
#pragma unroll
        for (int mt = 0; mt < 4; ++mt)
#pragma unroll
            for (int reg = 0; reg < 4; ++reg) {
                int j = mt * 16 + q4 * 4 + reg;
                int jj = j < 49 ? j : 48;
                int yj = jj / 7, xj = jj - yj * 7;
                int oj = (yj * 13 + xj) * 4;
                int rj = regl[jj];
#pragma unroll
                for (int nt = 0; nt < 4; ++nt) {
                    float v = acc[mt][nt][reg] * SCALE_ + biasl[bc[nt] - oj];
                    if (rj != rc[nt]) v -= 100.f;
                    s[mt][nt][reg] = (j < 49) ? v : -1e30f;
                }
            }
    }
    float sm[4];
#pragma unroll
    for (int nt = 0; nt < 4; ++nt) {
        float m = s[0][nt][0];
#pragma unroll
        for (int mt = 0; mt < 4; ++mt)
#pragma unroll
            for (int reg = 0; reg < 4; ++reg) m = fmaxf(m, s[mt][nt][reg]);
        m = fmaxf(m, __shfl_xor(m, 16, 64));
        m = fmaxf(m, __shfl_xor(m, 32, 64));
        float t = 0.f;
#pragma unroll
        for (int mt = 0; mt < 4; ++mt)
#pragma unroll
            for (int reg = 0; reg < 4; ++reg) {
                float e = __expf(s[mt][nt][reg] - m);
                s[mt][nt][reg] = e;
                t += e;
            }
        t += __shfl_xor(t, 16, 64);
        t += __shfl_xor(t, 32, 64);
        sm[nt] = 1.f / t;
    }
    u16* Ph = Pl + h * 4096;
#pragma unroll
    for (int nt = 0; nt < 4; ++nt) {
        int r = nt * 16 + colb;
        u32 sw = (u32)(r & 7) << 4;
#pragma unroll
        for (int mt = 0; mt < 4; ++mt) {
            u32x2 pk;
            pk[0] = cvtpk(s[mt][nt][0] * sm[nt], s[mt][nt][1] * sm[nt]);
            pk[1] = cvtpk(s[mt][nt][2] * sm[nt], s[mt][nt][3] * sm[nt]);
            u32 off = ((u32)((r * 64 + mt * 16 + q4 * 4) * 2)) ^ sw;
            *(u32x2*)((char*)Ph + off) = pk;
        }
    }
    short8 vb[2][2];
#pragma unroll
    for (int no = 0; no < 2; ++no)
#pragma unroll
        for (int ks = 0; ks < 2; ++ks)
            vb[no][ks] = *(const short8*)(Vt + (h * 32 + no * 16 + colb) * 72 + ks * 32 + q4 * 8);
#pragma unroll
    for (int mo = 0; mo < 4; ++mo) {
        int r = mo * 16 + colb;
        u32 sw = (u32)(r & 7) << 4;
        short8 pa[2];
#pragma unroll
        for (int ks = 0; ks < 2; ++ks) {
            u32 off = ((u32)((r * 64 + ks * 32 + q4 * 8) * 2)) ^ sw;
            pa[ks] = *(const short8*)((const char*)Ph + off);
        }
        f32x4 o0 = {0.f, 0.f, 0.f, 0.f}, o1 = {0.f, 0.f, 0.f, 0.f};
#pragma unroll
        for (int ks = 0; ks < 2; ++ks) {
            o0 = __builtin_amdgcn_mfma_f32_16x16x32_bf16(pa[ks], vb[0][ks], o0, 0, 0, 0);
            o1 = __builtin_amdgcn_mfma_f32_16x16x32_bf16(pa[ks], vb[1][ks], o1, 0, 0, 0);
        }
#pragma unroll
        for (int reg = 0; reg < 4; ++reg) {
            int orow = mo * 16 + q4 * 4 + reg;
            if (orow < 49) {
                size_t o = ((size_t)w * 49 + orow) * 128 + h * 32;
                outA[o + colb]      = f2bf(o0[reg]);
                outA[o + 16 + colb] = f2bf(o1[reg]);
            }
        }
    }
}

// ================= proj GEMM + reverse/roll + residual + LN2 stats, grid (1568) ========
// wave geometry 8x1 (16 rows x 128 cols) so LN2 stats reduce in-wave.
__global__ __launch_bounds__(512) void g_proj(const u16* __restrict__ attnO,
                                              const u16* __restrict__ projT,
                                              const float* __restrict__ bproj,
                                              const float* __restrict__ x,
                                              u16* __restrict__ x1,
                                              float2* __restrict__ stats) {
    __shared__ __align__(16) char As[32768], Bs[32768];
    int tid = threadIdx.x;
    int mb = blockIdx.x;
    stage_tile(As, (const char*)(attnO + (size_t)mb * 128 * 128), 256, tid);
    stage_tile(Bs, (const char*)projT, 256, tid);
    __syncthreads();
    int lane = tid & 63, wv = tid >> 6, colb = lane & 15, q4 = lane >> 4;
    int m0 = wv * 16;
    f32x4 acc[1][8] = {};
    mfma_core<1, 8>(As, Bs, m0, 0, colb, q4, acc);
    float bias[8];
#pragma unroll
    for (int nf = 0; nf < 8; ++nf) bias[nf] = bproj[nf * 16 + colb];
#pragma unroll
    for (int r = 0; r < 4; ++r) {
        int m = mb * 128 + m0 + q4 * 4 + r;
        int wn = m / 49, nn = m - wn * 49;
        int b = wn >> 6, wl = wn & 63;
        int ys = (wl >> 3) * 7 + nn / 7, xs = (wl & 7) * 7 + nn % 7;
        int y = ys + 3; if (y >= 56) y -= 56;
        int xx = xs + 3; if (xx >= 56) xx -= 56;
        size_t tok = (size_t)b * 3136 + y * 56 + xx;
        float v[8], s = 0.f;
#pragma unroll
        for (int nf = 0; nf < 8; ++nf) {
            v[nf] = acc[0][nf][r] + bias[nf] + x[tok * 128 + nf * 16 + colb];
            s += v[nf];
        }
#pragma unroll
        for (int off = 1; off < 16; off <<= 1) s += __shfl_xor(s, off, 64);
        float mu = s * (1.f / 128.f);
        float s2 = 0.f;
#pragma unroll
        for (int nf = 0; nf < 8; ++nf) { float d = v[nf] - mu; s2 += d * d; }
#pragma unroll
        for (int off = 1; off < 16; off <<= 1) s2 += __shfl_xor(s2, off, 64);
        float rs = rsqrtf(s2 * (1.f / 128.f) + 1e-3f);
#pragma unroll
        for (int nf = 0; nf < 8; ++nf)
            x1[tok * 128 + nf * 16 + colb] = f2bf(v[nf]);
        if (colb == 0) stats[tok] = make_float2(rs, rs * mu);
    }
}

// ================= FC1 (LN2 folded) + exact GELU, grid (1568, 4) =================
__global__ __launch_bounds__(512) void g_fc1(const u16* __restrict__ x1,
                                             const u16* __restrict__ fc1T,
                                             const float* __restrict__ beff,
                                             const float* __restrict__ csum,
                                             const float2* __restrict__ stats,
                                             u16* __restrict__ h1) {
    __shared__ __align__(16) char As[32768], Bs[32768];
    int tid = threadIdx.x;
    int mb = blockIdx.x, nb = blockIdx.y;
    stage_tile(As, (const char*)(x1 + (size_t)mb * 128 * 128), 256, tid);
    stage_tile(Bs, (const char*)(fc1T + (size_t)nb * 128 * 128), 256, tid);
    __syncthreads();
    int lane = tid & 63, wv = tid >> 6, colb = lane & 15, q4 = lane >> 4;
    int m0 = (wv >> 1) * 32, n0 = (wv & 1) * 64;
    f32x4 acc[2][4] = {};
    mfma_core<2, 4>(As, Bs, m0, n0, colb, q4, acc);
    float bb[4], cs[4];
#pragma unroll
    for (int nf = 0; nf < 4; ++nf) {
        int col = nb * 128 + n0 + nf * 16 + colb;
        bb[nf] = beff[col];
        cs[nf] = csum[col];
    }
#pragma unroll
    for (int mf = 0; mf < 2; ++mf)
#pragma unroll
        for (int r = 0; r < 4; ++r) {
            int row = mb * 128 + m0 + mf * 16 + q4 * 4 + r;
            float2 st = stats[row];
#pragma unroll
            for (int nf = 0; nf < 4; ++nf) {
                float t = st.x * acc[mf][nf][r] - st.y * cs[nf] + bb[nf];
                float g = 0.5f * t * (1.f + erff(t * 0.70710678118654752f));
                h1[(size_t)row * 512 + nb * 128 + n0 + nf * 16 + colb] = f2bf(g);
            }
        }
}

// ================= FC2 + final residual, grid (1568), K-loop of 4 =================
__global__ __launch_bounds__(512) void g_fc2(const u16* __restrict__ h1,
                                             const u16* __restrict__ fc2T,
                                             const float* __restrict__ b2,
                                             const u16* __restrict__ x1,
                                             float* __restrict__ out) {
    __shared__ __align__(16) char As[32768], Bs[32768];
    int tid = threadIdx.x;
    int mb = blockIdx.x;
    int lane = tid & 63, wv = tid >> 6, colb = lane & 15, q4 = lane >> 4;
    int m0 = (wv >> 1) * 32, n0 = (wv & 1) * 64;
    f32x4 acc[2][4] = {};
#pragma unroll 1
    for (int kt = 0; kt < 4; ++kt) {
        stage_tile(As, (const char*)h1 + (size_t)mb * 128 * 1024 + kt * 256, 1024, tid);
        stage_tile(Bs, (const char*)fc2T + kt * 256, 1024, tid);
        __syncthreads();
        mfma_core<2, 4>(As, Bs, m0, n0, colb, q4, acc);
        __syncthreads();
    }
#pragma unroll
    for (int nf = 0; nf < 4; ++nf) {
        int col = n0 + nf * 16 + colb;
        float bb = b2[col];
#pragma unroll
        for (int mf = 0; mf < 2; ++mf)
#pragma unroll
            for (int r = 0; r < 4; ++r) {
                size_t row = (size_t)mb * 128 + m0 + mf * 16 + q4 * 4 + r;
                out[row * 128 + col] = acc[mf][nf][r] + bb + bf2f(x1[row * 128 + col]);
            }
    }
}

extern "C" void kernel_launch(void* const* d_in, const int* in_sizes, int n_in,
                              void* d_out, int out_size, void* d_ws, size_t ws_size,
                              hipStream_t stream) {
    const float* x    = (const float*)d_in[0];
    const float* g1   = (const float*)d_in[1];
    const float* be1  = (const float*)d_in[2];
    const float* Wqkv = (const float*)d_in[3];
    const float* bqkv = (const float*)d_in[4];
    const float* relT = (const float*)d_in[5];
    const float* Wproj= (const float*)d_in[6];
    const float* bproj= (const float*)d_in[7];
    const float* g2   = (const float*)d_in[8];
    const float* be2  = (const float*)d_in[9];
    const float* Wfc1 = (const float*)d_in[10];
    const float* bfc1 = (const float*)d_in[11];
    const float* Wfc2 = (const float*)d_in[12];
    const float* bfc2 = (const float*)d_in[13];
    float* out = (float*)d_out;
    char* ws = (char*)d_ws;

    u16* qkvb    = (u16*)(ws + 0);              // 154,140,672  dead after k_attn
    u16* attnO   = (u16*)(ws + 154140672ULL);   //  51,380,224  dead after g_proj
    u16* xw      = (u16*)(ws + 205520896ULL);   //  51,380,224  dead after g_qkv
    u16* x1      = (u16*)(ws + 256901120ULL);   //  51,380,224  lives to g_fc2
    float2* stats= (float2*)(ws + 308281344ULL);//   1,605,632
    u16* h1      = (u16*)(ws + 0);              // 205,520,896  overwrites qkvb/attnO
    char* wb     = ws + 309886976ULL;
    u16* qkvT  = (u16*)(wb);                    // 98,304
    u16* projT = (u16*)(wb + 98304);            // 32,768
    u16* fc2T  = (u16*)(wb + 131072);           // 131,072
    u16* fc1T  = (u16*)(wb + 262144);           // 131,072
    float* beff1 = (float*)(wb + 393216);       // 2,048
    float* csum1 = (float*)(wb + 395264);       // 2,048

    k_transpose<<<dim3((128 * 384 + 255) / 256), dim3(256), 0, stream>>>(Wqkv, qkvT, 128, 384);
    k_transpose<<<dim3((128 * 128 + 255) / 256), dim3(256), 0, stream>>>(Wproj, projT, 128, 128);
    k_transpose<<<dim3((512 * 128 + 255) / 256), dim3(256), 0, stream>>>(Wfc2, fc2T, 512, 128);
    k_prep2<<<dim3(512), dim3(128), 0, stream>>>(Wfc1, g2, be2, bfc1, fc1T, beff1, csum1);

    k_ln1<<<dim3(NTOK / 4), dim3(256), 0, stream>>>(x, g1, be1, xw);
    g_qkv<<<dim3(MBLK, 3), dim3(512), 0, stream>>>(xw, qkvT, bqkv, qkvb);
    k_attn<<<dim3(NWIN), dim3(256), 0, stream>>>(qkvb, relT, attnO);
    g_proj<<<dim3(MBLK), dim3(512), 0, stream>>>(attnO, projT, bproj, x, x1, stats);
    g_fc1<<<dim3(MBLK, 4), dim3(512), 0, stream>>>(x1, fc1T, beff1, csum1, stats, h1);
    g_fc2<<<dim3(MBLK), dim3(512), 0, stream>>>(h1, fc2T, bfc2, x1, out);
}

// Round 7
// 399.961 us; speedup vs baseline: 1.9280x; 1.0451x over previous
//
#include <hip/hip_runtime.h>
#include <math.h>

typedef unsigned short u16;
typedef unsigned int u32;
typedef __attribute__((ext_vector_type(8))) short short8;
typedef __attribute__((ext_vector_type(2))) unsigned int u32x2;
typedef __attribute__((ext_vector_type(4))) float f32x4;

#define C_ 128
#define NTOK 200704   // B*H*W = 64*56*56
#define MBLK 1568     // NTOK / 128
#define NWIN 4096     // B * 64
#define SCALE_ 0.17677669529663687f

static __device__ __forceinline__ float bf2f(u16 u) {
    return __uint_as_float(((u32)u) << 16);
}
static __device__ __forceinline__ u16 f2bf(float f) {
    u32 u = __float_as_uint(f);
    u32 r = u + 0x7FFFu + ((u >> 16) & 1u);
    return (u16)(r >> 16);
}
static __device__ __forceinline__ u32 cvtpk(float a, float b) {
    u32 r;
    asm("v_cvt_pk_bf16_f32 %0, %1, %2" : "=v"(r) : "v"(a), "v"(b));
    return r;
}

// ================= weight prep =================
__global__ void k_transpose(const float* __restrict__ W, u16* __restrict__ Wt, int K, int N) {
    int i = blockIdx.x * 256 + threadIdx.x;
    if (i >= K * N) return;
    int k = i / N, n = i % N;
    Wt[(size_t)n * K + k] = f2bf(W[i]);
}

// fc1 prep: Wt[n][k]=bf16(W[k][n]*g2[k]); beff[n]=b[n]+sum be2[k]W[k][n]; csum[n]=sum Wt
__global__ __launch_bounds__(128) void k_prep2(const float* __restrict__ W,
                                               const float* __restrict__ g,
                                               const float* __restrict__ be,
                                               const float* __restrict__ b,
                                               u16* __restrict__ Wt,
                                               float* __restrict__ beff,
                                               float* __restrict__ csum) {
    const int N = 512;
    int n = blockIdx.x, k = threadIdx.x;
    float w = W[(size_t)k * N + n];
    u16 wp = f2bf(w * g[k]);
    Wt[(size_t)n * 128 + k] = wp;
    __shared__ float r1[128], r2[128];
    r1[k] = be[k] * w;
    r2[k] = bf2f(wp);
    __syncthreads();
    for (int s = 64; s > 0; s >>= 1) {
        if (k < s) { r1[k] += r1[k + s]; r2[k] += r2[k + s]; }
        __syncthreads();
    }
    if (k == 0) { beff[n] = b[n] + r1[0]; csum[n] = r2[0]; }
}

// ================= LN1 + roll(-3,-3) + window partition -> xw bf16 =================
__global__ __launch_bounds__(256) void k_ln1(const float* __restrict__ x,
                                             const float* __restrict__ g,
                                             const float* __restrict__ be,
                                             u16* __restrict__ xw) {
    int lane = threadIdx.x & 63, wv = threadIdx.x >> 6;
    int t = blockIdx.x * 4 + wv;
    const float* px = x + (size_t)t * C_;
    float2 v = *(const float2*)(px + lane * 2);
    float s = v.x + v.y;
#pragma unroll
    for (int off = 1; off < 64; off <<= 1) s += __shfl_xor(s, off, 64);
    float mu = s * (1.f / 128.f);
    float dx = v.x - mu, dy = v.y - mu;
    float s2 = dx * dx + dy * dy;
#pragma unroll
    for (int off = 1; off < 64; off <<= 1) s2 += __shfl_xor(s2, off, 64);
    float rs = rsqrtf(s2 * (1.f / 128.f) + 1e-3f);
    float2 gg = *(const float2*)(g + lane * 2);
    float2 bb = *(const float2*)(be + lane * 2);
    float o0 = dx * rs * gg.x + bb.x;
    float o1 = dy * rs * gg.y + bb.y;
    int b = t / 3136, p = t % 3136;
    int y = p / 56, xx = p % 56;
    int ys = y + 53; if (ys >= 56) ys -= 56;
    int xs = xx + 53; if (xs >= 56) xs -= 56;
    int w = (b << 6) | ((ys / 7) << 3) | (xs / 7);
    int n = (ys % 7) * 7 + (xs % 7);
    u16 o[2] = {f2bf(o0), f2bf(o1)};
    *(u32*)(xw + ((size_t)w * 49 + n) * C_ + lane * 2) = *(u32*)o;
}

// ================= LDS-staged block GEMM core =================
// Tile: 128 rows x 128 k, bf16, XOR swizzle: byte ^= (row&7)<<4.
static __device__ __forceinline__ void stage_tile(char* lds, const char* src, int row_stride, int tid) {
#pragma unroll
    for (int i = 0; i < 4; ++i) {
        int chunk = tid + i * 512;
        int row = chunk >> 4, k16 = (chunk & 15) << 4;
        short8 v = *(const short8*)(src + (size_t)row * row_stride + k16);
        *(short8*)(lds + (((row << 8) + k16) ^ ((row & 7) << 4))) = v;
    }
}
static __device__ __forceinline__ short8 ldsfrag(const char* lds, int row, int kb) {
    return *(const short8*)(lds + (((row << 8) + kb) ^ ((row & 7) << 4)));
}
template <int MR, int NR>
static __device__ __forceinline__ void mfma_core(const char* As, const char* Bs,
                                                 int m0, int n0, int colb, int q4,
                                                 f32x4 (&acc)[MR][NR]) {
#pragma unroll
    for (int ks = 0; ks < 4; ++ks) {
        int kb = ks * 64 + q4 * 16;
        short8 a[MR], b[NR];
#pragma unroll
        for (int m = 0; m < MR; ++m) a[m] = ldsfrag(As, m0 + m * 16 + colb, kb);
#pragma unroll
        for (int n = 0; n < NR; ++n) b[n] = ldsfrag(Bs, n0 + n * 16 + colb, kb);
#pragma unroll
        for (int m = 0; m < MR; ++m)
#pragma unroll
            for (int n = 0; n < NR; ++n)
                acc[m][n] = __builtin_amdgcn_mfma_f32_16x16x32_bf16(a[m], b[n], acc[m][n], 0, 0, 0);
    }
}

// ================= QKV GEMM: A staged once, loop 3 B-tiles. grid (1568) =================
__global__ __launch_bounds__(512) void g_qkv(const u16* __restrict__ xw,
                                             const u16* __restrict__ qkvT,
                                             const float* __restrict__ bq,
                                             u16* __restrict__ out) {
    __shared__ __align__(16) char As[32768], Bs[32768];
    int tid = threadIdx.x;
    int mb = blockIdx.x;
    stage_tile(As, (const char*)(xw + (size_t)mb * 128 * 128), 256, tid);
    int lane = tid & 63, wv = tid >> 6, colb = lane & 15, q4 = lane >> 4;
    int m0 = (wv >> 1) * 32, n0 = (wv & 1) * 64;
#pragma unroll 1
    for (int nb = 0; nb < 3; ++nb) {
        stage_tile(Bs, (const char*)(qkvT + (size_t)nb * 128 * 128), 256, tid);
        __syncthreads();
        f32x4 acc[2][4] = {};
        mfma_core<2, 4>(As, Bs, m0, n0, colb, q4, acc);
#pragma unroll
        for (int nf = 0; nf < 4; ++nf) {
            int col = nb * 128 + n0 + nf * 16 + colb;
            float bb = bq[col];
#pragma unroll
            for (int mf = 0; mf < 2; ++mf)
#pragma unroll
                for (int r = 0; r < 4; ++r) {
                    int row = mb * 128 + m0 + mf * 16 + q4 * 4 + r;
                    out[(size_t)row * 384 + col] = f2bf(acc[mf][nf][r] + bb);
                }
        }
        __syncthreads();
    }
}

// ================= MFMA window attention (unchanged) =================
__global__ __launch_bounds__(256) void k_attn(const u16* __restrict__ qkv,
                                              const float* __restrict__ relTab,
                                              u16* __restrict__ outA) {
    __shared__ u16 Pl[4 * 64 * 64];
    __shared__ u16 Vt[4 * 32 * 72];
    __shared__ float biasl[676];
    __shared__ int regl[64];
    int tid = threadIdx.x;
    int w = blockIdx.x;
    int wi = w & 63, wr = wi >> 3, wc = wi & 7;
    const u16* base = qkv + (size_t)w * 49 * 384;

    for (int task = tid; task < 1024; task += 256) {
        int row = task >> 3, jo = (task & 7) * 8;
        int h = row >> 5, d = row & 31;
        short8 v;
#pragma unroll
        for (int e = 0; e < 8; ++e) {
            int j = jo + e;
            v[e] = (j < 49) ? (short)base[j * 384 + 256 + h * 32 + d] : (short)0;
        }
        *(short8*)(Vt + row * 72 + jo) = v;
    }
    for (int idx = tid; idx < 676; idx += 256) biasl[idx] = relTab[idx];
    if (tid < 64) {
        int t = tid;
        int ty = t / 7, tx = t - ty * 7;
        int gy = wr * 7 + ty, gx = wc * 7 + tx;
        int rg = (gy < 49 ? 0 : (gy < 53 ? 1 : 2)) * 3 + (gx < 49 ? 0 : (gx < 53 ? 1 : 2));
        regl[t] = (t < 49) ? rg : 99;
    }
    __syncthreads();

    int lane = tid & 63, h = tid >> 6;
    int colb = lane & 15, q4 = lane >> 4;

    short8 ka[4], qb[4];
#pragma unroll
    for (int t = 0; t < 4; ++t) {
        int row = w * 49 + t * 16 + colb;
        if (row > NTOK - 1) row = NTOK - 1;
        ka[t] = *(const short8*)(qkv + (size_t)row * 384 + 128 + h * 32 + q4 * 8);
        qb[t] = *(const short8*)(qkv + (size_t)row * 384 + h * 32 + q4 * 8);
    }
    float s[4][4][4];
    {
        f32x4 acc[4][4];
#pragma unroll
        for (int mt = 0; mt < 4; ++mt)
#pragma unroll
            for (int nt = 0; nt < 4; ++nt)
                acc[mt][nt] = __builtin_amdgcn_mfma_f32_16x16x32_bf16(
                    ka[mt], qb[nt], (f32x4){0.f, 0.f, 0.f, 0.f}, 0, 0, 0);
        int bc[4], rc[4];
#pragma unroll
        for (int nt = 0; nt < 4; ++nt) {
            int c = nt * 16 + colb;
            int cc = c < 49 ? c : 48;
            int yc = cc / 7, xc = cc - yc * 7;
            bc[nt] = ((yc + 6) * 13 + (xc + 6)) * 4 + h;
            rc[nt] = regl[cc];
        }
#pragma unroll
        for (int mt = 0; mt < 4; ++mt)
#pragma unroll
            for (int reg = 0; reg < 4; ++reg) {
                int j = mt * 16 + q4 * 4 + reg;
                int jj = j < 49 ? j : 48;
                int yj = jj / 7, xj = jj - yj * 7;
                int oj = (yj * 13 + xj) * 4;
                int rj = regl[jj];
#pragma unroll
                for (int nt = 0; nt < 4; ++nt) {
                    float v = acc[mt][nt][reg] * SCALE_ + biasl[bc[nt] - oj];
                    if (rj != rc[nt]) v -= 100.f;
                    s[mt][nt][reg] = (j < 49) ? v : -1e30f;
                }
            }
    }
    float sm[4];
#pragma unroll
    for (int nt = 0; nt < 4; ++nt) {
        float m = s[0][nt][0];
#pragma unroll
        for (int mt = 0; mt < 4; ++mt)
#pragma unroll
            for (int reg = 0; reg < 4; ++reg) m = fmaxf(m, s[mt][nt][reg]);
        m = fmaxf(m, __shfl_xor(m, 16, 64));
        m = fmaxf(m, __shfl_xor(m, 32, 64));
        float t = 0.f;
#pragma unroll
        for (int mt = 0; mt < 4; ++mt)
#pragma unroll
            for (int reg = 0; reg < 4; ++reg) {
                float e = __expf(s[mt][nt][reg] - m);
                s[mt][nt][reg] = e;
                t += e;
            }
        t += __shfl_xor(t, 16, 64);
        t += __shfl_xor(t, 32, 64);
        sm[nt] = 1.f / t;
    }
    u16* Ph = Pl + h * 4096;
#pragma unroll
    for (int nt = 0; nt < 4; ++nt) {
        int r = nt * 16 + colb;
        u32 sw = (u32)(r & 7) << 4;
#pragma unroll
        for (int mt = 0; mt < 4; ++mt) {
            u32x2 pk;
            pk[0] = cvtpk(s[mt][nt][0] * sm[nt], s[mt][nt][1] * sm[nt]);
            pk[1] = cvtpk(s[mt][nt][2] * sm[nt], s[mt][nt][3] * sm[nt]);
            u32 off = ((u32)((r * 64 + mt * 16 + q4 * 4) * 2)) ^ sw;
            *(u32x2*)((char*)Ph + off) = pk;
        }
    }
    short8 vb[2][2];
#pragma unroll
    for (int no = 0; no < 2; ++no)
#pragma unroll
        for (int ks = 0; ks < 2; ++ks)
            vb[no][ks] = *(const short8*)(Vt + (h * 32 + no * 16 + colb) * 72 + ks * 32 + q4 * 8);
#pragma unroll
    for (int mo = 0; mo < 4; ++mo) {
        int r = mo * 16 + colb;
        u32 sw = (u32)(r & 7) << 4;
        short8 pa[2];
#pragma unroll
        for (int ks = 0; ks < 2; ++ks) {
            u32 off = ((u32)((r * 64 + ks * 32 + q4 * 8) * 2)) ^ sw;
            pa[ks] = *(const short8*)((const char*)Ph + off);
        }
        f32x4 o0 = {0.f, 0.f, 0.f, 0.f}, o1 = {0.f, 0.f, 0.f, 0.f};
#pragma unroll
        for (int ks = 0; ks < 2; ++ks) {
            o0 = __builtin_amdgcn_mfma_f32_16x16x32_bf16(pa[ks], vb[0][ks], o0, 0, 0, 0);
            o1 = __builtin_amdgcn_mfma_f32_16x16x32_bf16(pa[ks], vb[1][ks], o1, 0, 0, 0);
        }
#pragma unroll
        for (int reg = 0; reg < 4; ++reg) {
            int orow = mo * 16 + q4 * 4 + reg;
            if (orow < 49) {
                size_t o = ((size_t)w * 49 + orow) * 128 + h * 32;
                outA[o + colb]      = f2bf(o0[reg]);
                outA[o + 16 + colb] = f2bf(o1[reg]);
            }
        }
    }
}

// ================= proj GEMM + reverse/roll + residual + LN2 stats, grid (1568) ========
__global__ __launch_bounds__(512) void g_proj(const u16* __restrict__ attnO,
                                              const u16* __restrict__ projT,
                                              const float* __restrict__ bproj,
                                              const float* __restrict__ x,
                                              u16* __restrict__ x1,
                                              float2* __restrict__ stats) {
    __shared__ __align__(16) char As[32768], Bs[32768];
    int tid = threadIdx.x;
    int mb = blockIdx.x;
    stage_tile(As, (const char*)(attnO + (size_t)mb * 128 * 128), 256, tid);
    stage_tile(Bs, (const char*)projT, 256, tid);
    __syncthreads();
    int lane = tid & 63, wv = tid >> 6, colb = lane & 15, q4 = lane >> 4;
    int m0 = wv * 16;
    f32x4 acc[1][8] = {};
    mfma_core<1, 8>(As, Bs, m0, 0, colb, q4, acc);
    float bias[8];
#pragma unroll
    for (int nf = 0; nf < 8; ++nf) bias[nf] = bproj[nf * 16 + colb];
#pragma unroll
    for (int r = 0; r < 4; ++r) {
        int m = mb * 128 + m0 + q4 * 4 + r;
        int wn = m / 49, nn = m - wn * 49;
        int b = wn >> 6, wl = wn & 63;
        int ys = (wl >> 3) * 7 + nn / 7, xs = (wl & 7) * 7 + nn % 7;
        int y = ys + 3; if (y >= 56) y -= 56;
        int xx = xs + 3; if (xx >= 56) xx -= 56;
        size_t tok = (size_t)b * 3136 + y * 56 + xx;
        float v[8], s = 0.f;
#pragma unroll
        for (int nf = 0; nf < 8; ++nf) {
            v[nf] = acc[0][nf][r] + bias[nf] + x[tok * 128 + nf * 16 + colb];
            s += v[nf];
        }
#pragma unroll
        for (int off = 1; off < 16; off <<= 1) s += __shfl_xor(s, off, 64);
        float mu = s * (1.f / 128.f);
        float s2 = 0.f;
#pragma unroll
        for (int nf = 0; nf < 8; ++nf) { float d = v[nf] - mu; s2 += d * d; }
#pragma unroll
        for (int off = 1; off < 16; off <<= 1) s2 += __shfl_xor(s2, off, 64);
        float rs = rsqrtf(s2 * (1.f / 128.f) + 1e-3f);
#pragma unroll
        for (int nf = 0; nf < 8; ++nf)
            x1[tok * 128 + nf * 16 + colb] = f2bf(v[nf]);
        if (colb == 0) stats[tok] = make_float2(rs, rs * mu);
    }
}

// ================= fused MLP: (LN2-folded FC1 + GELU) -> FC2 + residual =================
// grid (1568). LDS: As = x1 tile (also residual source), Bs = W1/W2 chunk, Hs = h chunk.
__global__ __launch_bounds__(512) void k_mlp(const u16* __restrict__ x1,
                                             const u16* __restrict__ fc1T,
                                             const float* __restrict__ beff,
                                             const float* __restrict__ csum,
                                             const float2* __restrict__ stats,
                                             const u16* __restrict__ fc2T,
                                             const float* __restrict__ b2,
                                             float* __restrict__ out) {
    __shared__ __align__(16) char As[32768], Bs[32768], Hs[32768];
    int tid = threadIdx.x;
    int mb = blockIdx.x;
    stage_tile(As, (const char*)(x1 + (size_t)mb * 128 * 128), 256, tid);
    int lane = tid & 63, wv = tid >> 6, colb = lane & 15, q4 = lane >> 4;
    int m0 = (wv >> 1) * 32, n0 = (wv & 1) * 64;
    // per-thread row stats (same rows for every nb chunk)
    float2 st[2][4];
#pragma unroll
    for (int mf = 0; mf < 2; ++mf)
#pragma unroll
        for (int r = 0; r < 4; ++r)
            st[mf][r] = stats[mb * 128 + m0 + mf * 16 + q4 * 4 + r];
    f32x4 acc2[2][4] = {};
    __syncthreads();
#pragma unroll 1
    for (int nb = 0; nb < 4; ++nb) {
        stage_tile(Bs, (const char*)(fc1T + (size_t)nb * 128 * 128), 256, tid);
        __syncthreads();
        f32x4 hacc[2][4] = {};
        mfma_core<2, 4>(As, Bs, m0, n0, colb, q4, hacc);
        float bb[4], cs[4];
#pragma unroll
        for (int nf = 0; nf < 4; ++nf) {
            int col = nb * 128 + n0 + nf * 16 + colb;
            bb[nf] = beff[col];
            cs[nf] = csum[col];
        }
#pragma unroll
        for (int mf = 0; mf < 2; ++mf)
#pragma unroll
            for (int r = 0; r < 4; ++r) {
                int rl = m0 + mf * 16 + q4 * 4 + r;
                u32 sw = (u32)(rl & 7) << 4;
#pragma unroll
                for (int nf = 0; nf < 4; ++nf) {
                    float t = st[mf][r].x * hacc[mf][nf][r] - st[mf][r].y * cs[nf] + bb[nf];
                    float g = 0.5f * t * (1.f + erff(t * 0.70710678118654752f));
                    u32 off = ((u32)((rl << 8) + ((n0 + nf * 16 + colb) << 1))) ^ sw;
                    *(u16*)(Hs + off) = f2bf(g);
                }
            }
        __syncthreads();                     // Hs complete; Bs reads done
        stage_tile(Bs, (const char*)fc2T + nb * 256, 1024, tid);
        __syncthreads();
        mfma_core<2, 4>(Hs, Bs, m0, n0, colb, q4, acc2);
        __syncthreads();                     // Hs/Bs reads done before next nb
    }
#pragma unroll
    for (int nf = 0; nf < 4; ++nf) {
        int col = n0 + nf * 16 + colb;
        float bb = b2[col];
#pragma unroll
        for (int mf = 0; mf < 2; ++mf)
#pragma unroll
            for (int r = 0; r < 4; ++r) {
                int rl = m0 + mf * 16 + q4 * 4 + r;
                u32 aoff = ((u32)((rl << 8) + (col << 1))) ^ ((u32)(rl & 7) << 4);
                float res = bf2f(*(const u16*)(As + aoff));
                out[((size_t)mb * 128 + rl) * 128 + col] = acc2[mf][nf][r] + bb + res;
            }
    }
}

extern "C" void kernel_launch(void* const* d_in, const int* in_sizes, int n_in,
                              void* d_out, int out_size, void* d_ws, size_t ws_size,
                              hipStream_t stream) {
    const float* x    = (const float*)d_in[0];
    const float* g1   = (const float*)d_in[1];
    const float* be1  = (const float*)d_in[2];
    const float* Wqkv = (const float*)d_in[3];
    const float* bqkv = (const float*)d_in[4];
    const float* relT = (const float*)d_in[5];
    const float* Wproj= (const float*)d_in[6];
    const float* bproj= (const float*)d_in[7];
    const float* g2   = (const float*)d_in[8];
    const float* be2  = (const float*)d_in[9];
    const float* Wfc1 = (const float*)d_in[10];
    const float* bfc1 = (const float*)d_in[11];
    const float* Wfc2 = (const float*)d_in[12];
    const float* bfc2 = (const float*)d_in[13];
    float* out = (float*)d_out;
    char* ws = (char*)d_ws;

    u16* qkvb    = (u16*)(ws + 0);              // 154,140,672  dead after k_attn
    u16* attnO   = (u16*)(ws + 154140672ULL);   //  51,380,224  dead after g_proj
    u16* xw      = (u16*)(ws + 205520896ULL);   //  51,380,224  dead after g_qkv
    u16* x1      = (u16*)(ws + 256901120ULL);   //  51,380,224  lives to k_mlp
    float2* stats= (float2*)(ws + 308281344ULL);//   1,605,632
    char* wb     = ws + 309886976ULL;
    u16* qkvT  = (u16*)(wb);                    // 98,304
    u16* projT = (u16*)(wb + 98304);            // 32,768
    u16* fc2T  = (u16*)(wb + 131072);           // 131,072
    u16* fc1T  = (u16*)(wb + 262144);           // 131,072
    float* beff1 = (float*)(wb + 393216);       // 2,048
    float* csum1 = (float*)(wb + 395264);       // 2,048

    k_transpose<<<dim3((128 * 384 + 255) / 256), dim3(256), 0, stream>>>(Wqkv, qkvT, 128, 384);
    k_transpose<<<dim3((128 * 128 + 255) / 256), dim3(256), 0, stream>>>(Wproj, projT, 128, 128);
    k_transpose<<<dim3((512 * 128 + 255) / 256), dim3(256), 0, stream>>>(Wfc2, fc2T, 512, 128);
    k_prep2<<<dim3(512), dim3(128), 0, stream>>>(Wfc1, g2, be2, bfc1, fc1T, beff1, csum1);

    k_ln1<<<dim3(NTOK / 4), dim3(256), 0, stream>>>(x, g1, be1, xw);
    g_qkv<<<dim3(MBLK), dim3(512), 0, stream>>>(xw, qkvT, bqkv, qkvb);
    k_attn<<<dim3(NWIN), dim3(256), 0, stream>>>(qkvb, relT, attnO);
    g_proj<<<dim3(MBLK), dim3(512), 0, stream>>>(attnO, projT, bproj, x, x1, stats);
    k_mlp<<<dim3(MBLK), dim3(512), 0, stream>>>(x1, fc1T, beff1, csum1, stats, fc2T, bfc2, out);
}